// Round 17
// baseline (86.359 us; speedup 1.0000x reference)
//
#include <hip/hip_runtime.h>
#include <stdint.h>

// ANFM: B=4096, F=26, V=20000, E=64, P=325 pairs.
// SINGLE FUSED KERNEL (r14/r16 structure). Round-17 change: OCCUPANCY
// 16 -> 24 waves/CU. Evidence: VALUBusy <=47% in every clean profile;
// work-reduction levers all null (r9 VALU, r13 fixed-cost, r15 chain,
// r16 DS-count). Changes: (1) W fragments read from LDS in-loop
// (-32 VGPR; DS ops proven free by r16), (2) launch_bounds(512,6)
// -> VGPR cap 85 >= ~70 live, (3) MLP h0/h1 LDS aliased over xwb/WT
// (dead after post-attn barrier) -> 41.4KB/block -> 3 blocks/CU.
// afmL NOT aliased (written while other waves still read xwb).
#define B_N 4096
#define F_N 26
#define V_N 20000
#define E_N 64
#define P_N 325
#define PT  21   // ceil(336/16) pair M-tiles (padded to 336 rows)
#define SPB 8    // samples per block

typedef __attribute__((ext_vector_type(8))) _Float16 half8;
typedef __attribute__((ext_vector_type(4))) _Float16 half4;
typedef __attribute__((ext_vector_type(4))) float floatx4;
typedef __attribute__((ext_vector_type(4))) unsigned int uint4v;

static __device__ __forceinline__ float h2lo(unsigned int v) {
    return (float)__builtin_bit_cast(_Float16, (unsigned short)(v & 0xffffu));
}
static __device__ __forceinline__ float h2hi(unsigned int v) {
    return (float)__builtin_bit_cast(_Float16, (unsigned short)(v >> 16));
}

__global__ __launch_bounds__(512, 6) void anfm_fused_kernel(
    const int* __restrict__ x_idx, const float* __restrict__ embed_w,
    const float* __restrict__ embed_b, const float* __restrict__ att_w,
    const float* __restrict__ att_b, const float* __restrict__ att_p,
    const float* __restrict__ w0, const float* __restrict__ b0,
    const float* __restrict__ w1, const float* __restrict__ b1,
    const float* __restrict__ w2, const float* __restrict__ b2,
    const float* __restrict__ bias, float* __restrict__ out)
{
    // attn-phase buffers aliased with mlp-phase buffers (disjoint lifetimes,
    // separated by the post-attn __syncthreads).
    __shared__ union {
        struct {
            _Float16 xwb[SPB][F_N][72];   // fp16 gathered embeds (pad 72)
            _Float16 WT[64][72];          // W^T fp16: WT[col][k] (pad 72)
        } a;
        struct {
            _Float16 h0L[16][264];        // relu(L0) fp16 (rows 8-15 dead)
            float    h1L[16][132];        // relu(L1) f32  (rows 8-15 dead)
        } m;
    } U;
    __shared__ unsigned short pijL[336];    // (i<<8)|j per pair
    __shared__ unsigned int abapL[64];      // packed fp16: lo=att_b, hi=att_p
    __shared__ _Float16 afmL[16][72];       // afm fp16 (rows 8-15 zero)
    __shared__ float    lrL[SPB];

    const int tid  = threadIdx.x;
    const int lane = tid & 63;
    const int wid  = tid >> 6;               // 0..7
    const int c16  = lane & 15;
    const int g    = lane >> 4;
    const int b    = blockIdx.x * SPB + wid; // sample owned by this wave

    // ---- phase A (wave-local, ISSUE EARLY): idx row, lr, embed gathers ----
    int myidx = (lane < F_N) ? x_idx[b * F_N + lane] : 0;
    float lv  = (lane < F_N) ? embed_b[lane * V_N + myidx] : 0.f;  // lr term
    float4 gv[7];
    #pragma unroll
    for (int it = 0; it < 7; it++) {
        int f = it * 4 + g;
        int fc = (f < F_N) ? f : 0;
        int idxf = __shfl(myidx, fc);
        const float4* src = reinterpret_cast<const float4*>(
            embed_w + ((size_t)(fc * V_N + idxf)) * E_N);
        gv[it] = src[c16];                   // in flight under staging below
    }

    // ---- phase B (cooperative): pair map, abap, W^T staging, afm zero ----
    if (tid < 336) {
        int p = tid;
        int i = 0, j = 1;
        if (p < P_N) {
            i = (int)((51.0f - sqrtf(2601.0f - 8.0f * (float)p)) * 0.5f);
            if (i * (51 - i) / 2 > p) i--;
            else if ((i + 1) * (50 - i) / 2 <= p) i++;
            j = p - i * (51 - i) / 2 + i + 1;
        }
        pijL[p] = (unsigned short)((i << 8) | j);
    } else if (tid < 400) {
        int n = tid - 336;
        unsigned short abh = __builtin_bit_cast(unsigned short, (_Float16)att_b[n]);
        unsigned short aph = __builtin_bit_cast(unsigned short, (_Float16)att_p[n]);
        abapL[n] = ((unsigned int)aph << 16) | (unsigned int)abh;
    }
    // zero dead rows 8..15 of afmL (576 halves)
    for (int z = tid; z < 576; z += 512) {
        int r = z / 72, c = z - r * 72;
        afmL[8 + r][c] = (_Float16)0.f;
    }
    // W^T staging: WT[col][k] = att_w[k][col]  (coalesced f32 read)
    for (int idx = tid; idx < 64 * 64; idx += 512) {
        int k = idx >> 6, col = idx & 63;
        U.a.WT[col][k] = (_Float16)att_w[idx];
    }

    // ---- write gathered embeds to own xwb slice (wave-local) ----
    #pragma unroll
    for (int it = 0; it < 7; it++) {
        int f = it * 4 + g;
        if (f < F_N) {
            float4 v = gv[it];
            half4 hv = {(_Float16)v.x, (_Float16)v.y, (_Float16)v.z, (_Float16)v.w};
            *reinterpret_cast<half4*>(&U.a.xwb[wid][f][c16 * 4]) = hv;
        }
    }
    __syncthreads();

    // packed (ab, ap) for this lane's 16 hidden units: ONE b128 per nt
    uint4v abap[4];
    #pragma unroll
    for (int nt = 0; nt < 4; nt++)
        abap[nt] = *reinterpret_cast<const uint4v*>(&abapL[nt * 16 + g * 4]);

    // ---- phase 2 (wave-local, FUSED): MFMA scores -> exp -> weighted acc ----
    // D = W^T(A) @ pairs^T(B): D col = lane&15 = pair, row = g*4+r = hidden n.
    // W fragments read from LDS per (tile, nt): k-slot (g,u) <-> k=s*32+8g+u.
    // Max-free exp: softmax shift-invariant, scores O(0.1) -> no overflow.
    float acf[16];
    #pragma unroll
    for (int u = 0; u < 16; u++) acf[u] = 0.f;
    float Zp = 0.f;

    #pragma unroll 1
    for (int t = 0; t < PT; t++) {
        int pk = pijL[t * 16 + c16];
        int ri = pk >> 8, rj = pk & 255;
        half8 af[2];
        #pragma unroll
        for (int s = 0; s < 2; s++) {
            half8 xv = *reinterpret_cast<const half8*>(&U.a.xwb[wid][ri][s * 32 + g * 8]);
            half8 yv = *reinterpret_cast<const half8*>(&U.a.xwb[wid][rj][s * 32 + g * 8]);
            af[s] = xv * yv;   // 4x v_pk_mul_f16
        }
        float scq = 0.f;
        #pragma unroll
        for (int nt = 0; nt < 4; nt++) {
            half8 bf0 = *reinterpret_cast<const half8*>(
                &U.a.WT[nt * 16 + c16][g * 8]);
            half8 bf1 = *reinterpret_cast<const half8*>(
                &U.a.WT[nt * 16 + c16][32 + g * 8]);
            floatx4 acc = {h2lo(abap[nt][0]), h2lo(abap[nt][1]),
                           h2lo(abap[nt][2]), h2lo(abap[nt][3])};
            acc = __builtin_amdgcn_mfma_f32_16x16x32_f16(bf0, af[0], acc, 0, 0, 0);
            acc = __builtin_amdgcn_mfma_f32_16x16x32_f16(bf1, af[1], acc, 0, 0, 0);
            #pragma unroll
            for (int r = 0; r < 4; r++)
                scq = fmaf(h2hi(abap[nt][r]), fmaxf(acc[r], 0.f), scq);
        }
        scq += __shfl_xor(scq, 16);   // reduce over g groups (hidden chunks)
        scq += __shfl_xor(scq, 32);
        float w = (t * 16 + c16 < P_N) ? __expf(scq) : 0.f;
        Zp += w;
        #pragma unroll
        for (int s = 0; s < 2; s++)
            #pragma unroll
            for (int u = 0; u < 8; u++)
                acf[s * 8 + u] = fmaf((float)af[s][u], w, acf[s * 8 + u]);  // fma_mix
    }

    // ---- reduce over the 16 pair-columns (c16) within each g-group ----
    #pragma unroll
    for (int msk = 1; msk <= 8; msk <<= 1) {
        Zp += __shfl_xor(Zp, msk);
        #pragma unroll
        for (int u = 0; u < 16; u++) acf[u] += __shfl_xor(acf[u], msk);
    }

    // ---- write afm (fp16) + lr to LDS for the MLP phase ----
    if (c16 == 0) {
        float rZ = 1.f / Zp;
        #pragma unroll
        for (int s = 0; s < 2; s++) {
            half4 o0 = {(_Float16)(acf[s * 8 + 0] * rZ), (_Float16)(acf[s * 8 + 1] * rZ),
                        (_Float16)(acf[s * 8 + 2] * rZ), (_Float16)(acf[s * 8 + 3] * rZ)};
            half4 o1 = {(_Float16)(acf[s * 8 + 4] * rZ), (_Float16)(acf[s * 8 + 5] * rZ),
                        (_Float16)(acf[s * 8 + 6] * rZ), (_Float16)(acf[s * 8 + 7] * rZ)};
            *reinterpret_cast<half4*>(&afmL[wid][s * 32 + g * 8])     = o0;
            *reinterpret_cast<half4*>(&afmL[wid][s * 32 + g * 8 + 4]) = o1;
        }
    }
    #pragma unroll
    for (int off = 32; off; off >>= 1) lv += __shfl_xor(lv, off);
    if (lane == 0) lrL[wid] = lv;
    __syncthreads();   // attn buffers (xwb/WT) dead past here -> MLP aliases

    // ================= MLP phase (in-block, r12-verified head) =============
    // mfma(A,B): D row = g*4+r (= A row index), D col = c16 (= B n index);
    // k-slot (g,u) <-> k = base + 8g + u, identical A and B.
    // Only D rows < 8 are real samples; rows 8-15 dead (afmL zeroed).

    // ---- L0: D[16,256] = afm @ w0 + b0, relu -> h0L. 16 n-tiles / 8 waves.
    {
        half8 af0[2];
        #pragma unroll
        for (int s = 0; s < 2; s++)
            af0[s] = *reinterpret_cast<const half8*>(&afmL[c16][s * 32 + g * 8]);
        #pragma unroll
        for (int q = 0; q < 2; q++) {
            int n = (wid * 2 + q) * 16 + c16;
            half8 bf[2];
            #pragma unroll
            for (int s = 0; s < 2; s++)
                #pragma unroll
                for (int u = 0; u < 8; u++)
                    bf[s][u] = (_Float16)w0[(s * 32 + g * 8 + u) * 256 + n];
            floatx4 acc = {0.f, 0.f, 0.f, 0.f};
            acc = __builtin_amdgcn_mfma_f32_16x16x32_f16(af0[0], bf[0], acc, 0, 0, 0);
            acc = __builtin_amdgcn_mfma_f32_16x16x32_f16(af0[1], bf[1], acc, 0, 0, 0);
            float b0n = b0[n];
            #pragma unroll
            for (int r = 0; r < 4; r++)
                U.m.h0L[g * 4 + r][n] = (_Float16)fmaxf(acc[r] + b0n, 0.f);
        }
    }
    __syncthreads();

    // ---- L1: D[16,128] = h0 @ w1 + b1, relu -> h1L. 8 n-tiles / 8 waves.
    {
        int n = wid * 16 + c16;
        floatx4 acc = {0.f, 0.f, 0.f, 0.f};
        #pragma unroll
        for (int ks = 0; ks < 8; ks++) {
            half8 af1 = *reinterpret_cast<const half8*>(&U.m.h0L[c16][ks * 32 + g * 8]);
            half8 bf;
            #pragma unroll
            for (int u = 0; u < 8; u++)
                bf[u] = (_Float16)w1[(ks * 32 + g * 8 + u) * 128 + n];
            acc = __builtin_amdgcn_mfma_f32_16x16x32_f16(af1, bf, acc, 0, 0, 0);
        }
        float b1n = b1[n];
        #pragma unroll
        for (int r = 0; r < 4; r++)
            U.m.h1L[g * 4 + r][n] = fmaxf(acc[r] + b1n, 0.f);
    }
    __syncthreads();

    // ---- L2: out = h1 @ w2 + b2 + bias + lr. Wave wid -> sample wid. ----
    {
        float part = fmaf(U.m.h1L[wid][lane * 2], w2[lane * 2],
                          U.m.h1L[wid][lane * 2 + 1] * w2[lane * 2 + 1]);
        #pragma unroll
        for (int off = 32; off; off >>= 1) part += __shfl_xor(part, off);
        if (lane == 0)
            out[blockIdx.x * SPB + wid] = part + b2[0] + bias[0] + lrL[wid];
    }
}

extern "C" void kernel_launch(void* const* d_in, const int* in_sizes, int n_in,
                              void* d_out, int out_size, void* d_ws, size_t ws_size,
                              hipStream_t stream) {
    const int*   x_idx   = (const int*)d_in[0];
    const float* embed_w = (const float*)d_in[1];
    const float* embed_b = (const float*)d_in[2];
    const float* att_w   = (const float*)d_in[3];
    const float* att_b   = (const float*)d_in[4];
    const float* att_p   = (const float*)d_in[5];
    const float* w0      = (const float*)d_in[6];
    const float* b0      = (const float*)d_in[7];
    const float* w1      = (const float*)d_in[8];
    const float* b1      = (const float*)d_in[9];
    const float* w2      = (const float*)d_in[10];
    const float* b2      = (const float*)d_in[11];
    const float* bias    = (const float*)d_in[12];
    float*       out     = (float*)d_out;

    anfm_fused_kernel<<<B_N / SPB, 512, 0, stream>>>(
        x_idx, embed_w, embed_b, att_w, att_b, att_p,
        w0, b0, w1, b1, w2, b2, bias, out);
}

// Round 18
// 34.309 us; speedup vs baseline: 2.5171x; 2.5171x over previous
//
#include <hip/hip_runtime.h>
#include <stdint.h>

// ANFM: B=4096, F=26, V=20000, E=64, P=325 pairs.
// FINAL KERNEL (byte-exact round-16, best measured: 34.25us).
// SINGLE FUSED KERNEL: 8 samples/block (512 thr), 1 wave/sample attn phase
// (fused MFMA->max-free-exp->online-weighted acc, unroll 1, cap 128 -- the
// ONLY clean codegen point; caps 40-102 all spilled across r2-r17) +
// in-block MFMA MLP phase (rows 8-15 of the M-tile dead).
// ab/ap packed fp16x2 in 16 regs; W-fragments in 32 regs; single barrier
// before phase 2.
// Lever ledger (attn ~29us): compute/fixed-cost/chain/DS-count all null;
// fusion -7.9us; occupancy/ILP increases -> spill. Latency plateau.
#define B_N 4096
#define F_N 26
#define V_N 20000
#define E_N 64
#define P_N 325
#define PT  21   // ceil(336/16) pair M-tiles (padded to 336 rows)
#define SPB 8    // samples per block

typedef __attribute__((ext_vector_type(8))) _Float16 half8;
typedef __attribute__((ext_vector_type(4))) _Float16 half4;
typedef __attribute__((ext_vector_type(4))) float floatx4;
typedef __attribute__((ext_vector_type(4))) unsigned int uint4v;

static __device__ __forceinline__ float h2lo(unsigned int v) {
    return (float)__builtin_bit_cast(_Float16, (unsigned short)(v & 0xffffu));
}
static __device__ __forceinline__ float h2hi(unsigned int v) {
    return (float)__builtin_bit_cast(_Float16, (unsigned short)(v >> 16));
}

__global__ __launch_bounds__(512, 4) void anfm_fused_kernel(
    const int* __restrict__ x_idx, const float* __restrict__ embed_w,
    const float* __restrict__ embed_b, const float* __restrict__ att_w,
    const float* __restrict__ att_b, const float* __restrict__ att_p,
    const float* __restrict__ w0, const float* __restrict__ b0,
    const float* __restrict__ w1, const float* __restrict__ b1,
    const float* __restrict__ w2, const float* __restrict__ b2,
    const float* __restrict__ bias, float* __restrict__ out)
{
    __shared__ _Float16 xwb[SPB][F_N][72];  // fp16 gathered embeds (pad 72)
    __shared__ _Float16 WT[64][72];         // W^T fp16: WT[col][k] (pad 72)
    __shared__ unsigned short pijL[336];    // (i<<8)|j per pair
    __shared__ unsigned int abapL[64];      // packed fp16: lo=att_b, hi=att_p
    __shared__ _Float16 afmL[16][72];       // afm fp16 (rows 8-15 zero)
    __shared__ _Float16 h0L[16][264];       // relu(L0) fp16 (rows 8-15 dead)
    __shared__ float    h1L[16][132];       // relu(L1) f32  (rows 8-15 dead)
    __shared__ float    lrL[SPB];

    const int tid  = threadIdx.x;
    const int lane = tid & 63;
    const int wid  = tid >> 6;               // 0..7
    const int c16  = lane & 15;
    const int g    = lane >> 4;
    const int b    = blockIdx.x * SPB + wid; // sample owned by this wave

    // ---- phase A (wave-local, ISSUE EARLY): idx row, lr, embed gathers ----
    int myidx = (lane < F_N) ? x_idx[b * F_N + lane] : 0;
    float lv  = (lane < F_N) ? embed_b[lane * V_N + myidx] : 0.f;  // lr term
    float4 gv[7];
    #pragma unroll
    for (int it = 0; it < 7; it++) {
        int f = it * 4 + g;
        int fc = (f < F_N) ? f : 0;
        int idxf = __shfl(myidx, fc);
        const float4* src = reinterpret_cast<const float4*>(
            embed_w + ((size_t)(fc * V_N + idxf)) * E_N);
        gv[it] = src[c16];                   // in flight under staging below
    }

    // ---- phase B (cooperative): pair map, abap, W^T staging, afm zero ----
    if (tid < 336) {
        int p = tid;
        int i = 0, j = 1;
        if (p < P_N) {
            i = (int)((51.0f - sqrtf(2601.0f - 8.0f * (float)p)) * 0.5f);
            if (i * (51 - i) / 2 > p) i--;
            else if ((i + 1) * (50 - i) / 2 <= p) i++;
            j = p - i * (51 - i) / 2 + i + 1;
        }
        pijL[p] = (unsigned short)((i << 8) | j);
    } else if (tid < 400) {
        int n = tid - 336;
        unsigned short abh = __builtin_bit_cast(unsigned short, (_Float16)att_b[n]);
        unsigned short aph = __builtin_bit_cast(unsigned short, (_Float16)att_p[n]);
        abapL[n] = ((unsigned int)aph << 16) | (unsigned int)abh;
    }
    // zero dead rows 8..15 of afmL (576 halves)
    for (int z = tid; z < 576; z += 512) {
        int r = z / 72, c = z - r * 72;
        afmL[8 + r][c] = (_Float16)0.f;
    }
    // W^T staging: WT[col][k] = att_w[k][col]  (coalesced f32 read)
    for (int idx = tid; idx < 64 * 64; idx += 512) {
        int k = idx >> 6, col = idx & 63;
        WT[col][k] = (_Float16)att_w[idx];
    }

    // ---- write gathered embeds to own xwb slice (wave-local) ----
    #pragma unroll
    for (int it = 0; it < 7; it++) {
        int f = it * 4 + g;
        if (f < F_N) {
            float4 v = gv[it];
            half4 hv = {(_Float16)v.x, (_Float16)v.y, (_Float16)v.z, (_Float16)v.w};
            *reinterpret_cast<half4*>(&xwb[wid][f][c16 * 4]) = hv;
        }
    }
    __syncthreads();

    // W fragments (rows of W^T) in registers; k-slot (g,u) <-> k = s*32+8g+u
    half8 bfr[4][2];
    #pragma unroll
    for (int nt = 0; nt < 4; nt++)
        #pragma unroll
        for (int s = 0; s < 2; s++)
            bfr[nt][s] = *reinterpret_cast<const half8*>(
                &WT[nt * 16 + c16][s * 32 + g * 8]);
    // packed (ab, ap) for this lane's 16 hidden units: ONE b128 per nt
    uint4v abap[4];
    #pragma unroll
    for (int nt = 0; nt < 4; nt++)
        abap[nt] = *reinterpret_cast<const uint4v*>(&abapL[nt * 16 + g * 4]);

    // ---- phase 2 (wave-local, FUSED): MFMA scores -> exp -> weighted acc ----
    // D = W^T(A) @ pairs^T(B): D col = lane&15 = pair, row = g*4+r = hidden n.
    // Max-free exp: softmax shift-invariant, scores O(0.1) -> no overflow.
    float acf[16];
    #pragma unroll
    for (int u = 0; u < 16; u++) acf[u] = 0.f;
    float Zp = 0.f;

    #pragma unroll 1
    for (int t = 0; t < PT; t++) {
        int pk = pijL[t * 16 + c16];
        int ri = pk >> 8, rj = pk & 255;
        half8 af[2];
        #pragma unroll
        for (int s = 0; s < 2; s++) {
            half8 xv = *reinterpret_cast<const half8*>(&xwb[wid][ri][s * 32 + g * 8]);
            half8 yv = *reinterpret_cast<const half8*>(&xwb[wid][rj][s * 32 + g * 8]);
            af[s] = xv * yv;   // 4x v_pk_mul_f16
        }
        float scq = 0.f;
        #pragma unroll
        for (int nt = 0; nt < 4; nt++) {
            floatx4 acc = {h2lo(abap[nt][0]), h2lo(abap[nt][1]),
                           h2lo(abap[nt][2]), h2lo(abap[nt][3])};
            acc = __builtin_amdgcn_mfma_f32_16x16x32_f16(bfr[nt][0], af[0], acc, 0, 0, 0);
            acc = __builtin_amdgcn_mfma_f32_16x16x32_f16(bfr[nt][1], af[1], acc, 0, 0, 0);
            #pragma unroll
            for (int r = 0; r < 4; r++)
                scq = fmaf(h2hi(abap[nt][r]), fmaxf(acc[r], 0.f), scq);
        }
        scq += __shfl_xor(scq, 16);   // reduce over g groups (hidden chunks)
        scq += __shfl_xor(scq, 32);
        float w = (t * 16 + c16 < P_N) ? __expf(scq) : 0.f;
        Zp += w;
        #pragma unroll
        for (int s = 0; s < 2; s++)
            #pragma unroll
            for (int u = 0; u < 8; u++)
                acf[s * 8 + u] = fmaf((float)af[s][u], w, acf[s * 8 + u]);  // fma_mix
    }

    // ---- reduce over the 16 pair-columns (c16) within each g-group ----
    #pragma unroll
    for (int msk = 1; msk <= 8; msk <<= 1) {
        Zp += __shfl_xor(Zp, msk);
        #pragma unroll
        for (int u = 0; u < 16; u++) acf[u] += __shfl_xor(acf[u], msk);
    }

    // ---- write afm (fp16) + lr to LDS for the MLP phase ----
    if (c16 == 0) {
        float rZ = 1.f / Zp;
        #pragma unroll
        for (int s = 0; s < 2; s++) {
            half4 o0 = {(_Float16)(acf[s * 8 + 0] * rZ), (_Float16)(acf[s * 8 + 1] * rZ),
                        (_Float16)(acf[s * 8 + 2] * rZ), (_Float16)(acf[s * 8 + 3] * rZ)};
            half4 o1 = {(_Float16)(acf[s * 8 + 4] * rZ), (_Float16)(acf[s * 8 + 5] * rZ),
                        (_Float16)(acf[s * 8 + 6] * rZ), (_Float16)(acf[s * 8 + 7] * rZ)};
            *reinterpret_cast<half4*>(&afmL[wid][s * 32 + g * 8])     = o0;
            *reinterpret_cast<half4*>(&afmL[wid][s * 32 + g * 8 + 4]) = o1;
        }
    }
    #pragma unroll
    for (int off = 32; off; off >>= 1) lv += __shfl_xor(lv, off);
    if (lane == 0) lrL[wid] = lv;
    __syncthreads();

    // ================= MLP phase (in-block, r12-verified head) =============
    // mfma(A,B): D row = g*4+r (= A row index), D col = c16 (= B n index);
    // k-slot (g,u) <-> k = base + 8g + u, identical A and B.
    // Only D rows < 8 are real samples; rows 8-15 dead (afmL zeroed).

    // ---- L0: D[16,256] = afm @ w0 + b0, relu -> h0L. 16 n-tiles / 8 waves.
    {
        half8 af0[2];
        #pragma unroll
        for (int s = 0; s < 2; s++)
            af0[s] = *reinterpret_cast<const half8*>(&afmL[c16][s * 32 + g * 8]);
        #pragma unroll
        for (int q = 0; q < 2; q++) {
            int n = (wid * 2 + q) * 16 + c16;
            half8 bf[2];
            #pragma unroll
            for (int s = 0; s < 2; s++)
                #pragma unroll
                for (int u = 0; u < 8; u++)
                    bf[s][u] = (_Float16)w0[(s * 32 + g * 8 + u) * 256 + n];
            floatx4 acc = {0.f, 0.f, 0.f, 0.f};
            acc = __builtin_amdgcn_mfma_f32_16x16x32_f16(af0[0], bf[0], acc, 0, 0, 0);
            acc = __builtin_amdgcn_mfma_f32_16x16x32_f16(af0[1], bf[1], acc, 0, 0, 0);
            float b0n = b0[n];
            #pragma unroll
            for (int r = 0; r < 4; r++)
                h0L[g * 4 + r][n] = (_Float16)fmaxf(acc[r] + b0n, 0.f);
        }
    }
    __syncthreads();

    // ---- L1: D[16,128] = h0 @ w1 + b1, relu -> h1L. 8 n-tiles / 8 waves.
    {
        int n = wid * 16 + c16;
        floatx4 acc = {0.f, 0.f, 0.f, 0.f};
        #pragma unroll
        for (int ks = 0; ks < 8; ks++) {
            half8 af1 = *reinterpret_cast<const half8*>(&h0L[c16][ks * 32 + g * 8]);
            half8 bf;
            #pragma unroll
            for (int u = 0; u < 8; u++)
                bf[u] = (_Float16)w1[(ks * 32 + g * 8 + u) * 128 + n];
            acc = __builtin_amdgcn_mfma_f32_16x16x32_f16(af1, bf, acc, 0, 0, 0);
        }
        float b1n = b1[n];
        #pragma unroll
        for (int r = 0; r < 4; r++)
            h1L[g * 4 + r][n] = fmaxf(acc[r] + b1n, 0.f);
    }
    __syncthreads();

    // ---- L2: out = h1 @ w2 + b2 + bias + lr. Wave wid -> sample wid. ----
    {
        float part = fmaf(h1L[wid][lane * 2], w2[lane * 2],
                          h1L[wid][lane * 2 + 1] * w2[lane * 2 + 1]);
        #pragma unroll
        for (int off = 32; off; off >>= 1) part += __shfl_xor(part, off);
        if (lane == 0)
            out[blockIdx.x * SPB + wid] = part + b2[0] + bias[0] + lrL[wid];
    }
}

extern "C" void kernel_launch(void* const* d_in, const int* in_sizes, int n_in,
                              void* d_out, int out_size, void* d_ws, size_t ws_size,
                              hipStream_t stream) {
    const int*   x_idx   = (const int*)d_in[0];
    const float* embed_w = (const float*)d_in[1];
    const float* embed_b = (const float*)d_in[2];
    const float* att_w   = (const float*)d_in[3];
    const float* att_b   = (const float*)d_in[4];
    const float* att_p   = (const float*)d_in[5];
    const float* w0      = (const float*)d_in[6];
    const float* b0      = (const float*)d_in[7];
    const float* w1      = (const float*)d_in[8];
    const float* b1      = (const float*)d_in[9];
    const float* w2      = (const float*)d_in[10];
    const float* b2      = (const float*)d_in[11];
    const float* bias    = (const float*)d_in[12];
    float*       out     = (float*)d_out;

    anfm_fused_kernel<<<B_N / SPB, 512, 0, stream>>>(
        x_idx, embed_w, embed_b, att_w, att_b, att_p,
        w0, b0, w1, b1, w2, b2, bias, out);
}

// Round 19
// 34.091 us; speedup vs baseline: 2.5332x; 1.0064x over previous
//
#include <hip/hip_runtime.h>
#include <stdint.h>

// ANFM: B=4096, F=26, V=20000, E=64, P=325 pairs.
// r16 structure (34.3us, triple-reproduced) with ONE change: the xor-32
// score reduce uses v_permlane32_swap_b32 (VALU, ~5cyc) instead of
// __shfl_xor(,32) (ds_bpermute, ~120cyc LDS crossbar on the per-tile
// critical path). Bit-identical math: rr.x+rr.y = x[l] + x[l^32].
// Everything else byte-identical to the known-good codegen point
// (cap 128, unroll 1 -- caps 40-102 all spilled across r2-r17).
#define B_N 4096
#define F_N 26
#define V_N 20000
#define E_N 64
#define P_N 325
#define PT  21   // ceil(336/16) pair M-tiles (padded to 336 rows)
#define SPB 8    // samples per block

typedef __attribute__((ext_vector_type(8))) _Float16 half8;
typedef __attribute__((ext_vector_type(4))) _Float16 half4;
typedef __attribute__((ext_vector_type(4))) float floatx4;
typedef __attribute__((ext_vector_type(4))) unsigned int uint4v;
typedef __attribute__((ext_vector_type(2))) unsigned int uint2v;

static __device__ __forceinline__ float h2lo(unsigned int v) {
    return (float)__builtin_bit_cast(_Float16, (unsigned short)(v & 0xffffu));
}
static __device__ __forceinline__ float h2hi(unsigned int v) {
    return (float)__builtin_bit_cast(_Float16, (unsigned short)(v >> 16));
}
// sum over lane pairs (l, l^32) via permlane32_swap: VALU pipe, no LDS.
static __device__ __forceinline__ float xor32_sum(float x) {
    unsigned int u = __builtin_bit_cast(unsigned int, x);
    uint2v rr = __builtin_amdgcn_permlane32_swap(u, u, false, false);
    return __builtin_bit_cast(float, rr.x) + __builtin_bit_cast(float, rr.y);
}

__global__ __launch_bounds__(512, 4) void anfm_fused_kernel(
    const int* __restrict__ x_idx, const float* __restrict__ embed_w,
    const float* __restrict__ embed_b, const float* __restrict__ att_w,
    const float* __restrict__ att_b, const float* __restrict__ att_p,
    const float* __restrict__ w0, const float* __restrict__ b0,
    const float* __restrict__ w1, const float* __restrict__ b1,
    const float* __restrict__ w2, const float* __restrict__ b2,
    const float* __restrict__ bias, float* __restrict__ out)
{
    __shared__ _Float16 xwb[SPB][F_N][72];  // fp16 gathered embeds (pad 72)
    __shared__ _Float16 WT[64][72];         // W^T fp16: WT[col][k] (pad 72)
    __shared__ unsigned short pijL[336];    // (i<<8)|j per pair
    __shared__ unsigned int abapL[64];      // packed fp16: lo=att_b, hi=att_p
    __shared__ _Float16 afmL[16][72];       // afm fp16 (rows 8-15 zero)
    __shared__ _Float16 h0L[16][264];       // relu(L0) fp16 (rows 8-15 dead)
    __shared__ float    h1L[16][132];       // relu(L1) f32  (rows 8-15 dead)
    __shared__ float    lrL[SPB];

    const int tid  = threadIdx.x;
    const int lane = tid & 63;
    const int wid  = tid >> 6;               // 0..7
    const int c16  = lane & 15;
    const int g    = lane >> 4;
    const int b    = blockIdx.x * SPB + wid; // sample owned by this wave

    // ---- phase A (wave-local, ISSUE EARLY): idx row, lr, embed gathers ----
    int myidx = (lane < F_N) ? x_idx[b * F_N + lane] : 0;
    float lv  = (lane < F_N) ? embed_b[lane * V_N + myidx] : 0.f;  // lr term
    float4 gv[7];
    #pragma unroll
    for (int it = 0; it < 7; it++) {
        int f = it * 4 + g;
        int fc = (f < F_N) ? f : 0;
        int idxf = __shfl(myidx, fc);
        const float4* src = reinterpret_cast<const float4*>(
            embed_w + ((size_t)(fc * V_N + idxf)) * E_N);
        gv[it] = src[c16];                   // in flight under staging below
    }

    // ---- phase B (cooperative): pair map, abap, W^T staging, afm zero ----
    if (tid < 336) {
        int p = tid;
        int i = 0, j = 1;
        if (p < P_N) {
            i = (int)((51.0f - sqrtf(2601.0f - 8.0f * (float)p)) * 0.5f);
            if (i * (51 - i) / 2 > p) i--;
            else if ((i + 1) * (50 - i) / 2 <= p) i++;
            j = p - i * (51 - i) / 2 + i + 1;
        }
        pijL[p] = (unsigned short)((i << 8) | j);
    } else if (tid < 400) {
        int n = tid - 336;
        unsigned short abh = __builtin_bit_cast(unsigned short, (_Float16)att_b[n]);
        unsigned short aph = __builtin_bit_cast(unsigned short, (_Float16)att_p[n]);
        abapL[n] = ((unsigned int)aph << 16) | (unsigned int)abh;
    }
    // zero dead rows 8..15 of afmL (576 halves)
    for (int z = tid; z < 576; z += 512) {
        int r = z / 72, c = z - r * 72;
        afmL[8 + r][c] = (_Float16)0.f;
    }
    // W^T staging: WT[col][k] = att_w[k][col]  (coalesced f32 read)
    for (int idx = tid; idx < 64 * 64; idx += 512) {
        int k = idx >> 6, col = idx & 63;
        WT[col][k] = (_Float16)att_w[idx];
    }

    // ---- write gathered embeds to own xwb slice (wave-local) ----
    #pragma unroll
    for (int it = 0; it < 7; it++) {
        int f = it * 4 + g;
        if (f < F_N) {
            float4 v = gv[it];
            half4 hv = {(_Float16)v.x, (_Float16)v.y, (_Float16)v.z, (_Float16)v.w};
            *reinterpret_cast<half4*>(&xwb[wid][f][c16 * 4]) = hv;
        }
    }
    __syncthreads();

    // W fragments (rows of W^T) in registers; k-slot (g,u) <-> k = s*32+8g+u
    half8 bfr[4][2];
    #pragma unroll
    for (int nt = 0; nt < 4; nt++)
        #pragma unroll
        for (int s = 0; s < 2; s++)
            bfr[nt][s] = *reinterpret_cast<const half8*>(
                &WT[nt * 16 + c16][s * 32 + g * 8]);
    // packed (ab, ap) for this lane's 16 hidden units: ONE b128 per nt
    uint4v abap[4];
    #pragma unroll
    for (int nt = 0; nt < 4; nt++)
        abap[nt] = *reinterpret_cast<const uint4v*>(&abapL[nt * 16 + g * 4]);

    // ---- phase 2 (wave-local, FUSED): MFMA scores -> exp -> weighted acc ----
    // D = W^T(A) @ pairs^T(B): D col = lane&15 = pair, row = g*4+r = hidden n.
    // Max-free exp: softmax shift-invariant, scores O(0.1) -> no overflow.
    float acf[16];
    #pragma unroll
    for (int u = 0; u < 16; u++) acf[u] = 0.f;
    float Zp = 0.f;

    #pragma unroll 1
    for (int t = 0; t < PT; t++) {
        int pk = pijL[t * 16 + c16];
        int ri = pk >> 8, rj = pk & 255;
        half8 af[2];
        #pragma unroll
        for (int s = 0; s < 2; s++) {
            half8 xv = *reinterpret_cast<const half8*>(&xwb[wid][ri][s * 32 + g * 8]);
            half8 yv = *reinterpret_cast<const half8*>(&xwb[wid][rj][s * 32 + g * 8]);
            af[s] = xv * yv;   // 4x v_pk_mul_f16
        }
        float scq = 0.f;
        #pragma unroll
        for (int nt = 0; nt < 4; nt++) {
            floatx4 acc = {h2lo(abap[nt][0]), h2lo(abap[nt][1]),
                           h2lo(abap[nt][2]), h2lo(abap[nt][3])};
            acc = __builtin_amdgcn_mfma_f32_16x16x32_f16(bfr[nt][0], af[0], acc, 0, 0, 0);
            acc = __builtin_amdgcn_mfma_f32_16x16x32_f16(bfr[nt][1], af[1], acc, 0, 0, 0);
            #pragma unroll
            for (int r = 0; r < 4; r++)
                scq = fmaf(h2hi(abap[nt][r]), fmaxf(acc[r], 0.f), scq);
        }
        scq += __shfl_xor(scq, 16);   // reduce over g (within 32 lanes: swizzle)
        scq = xor32_sum(scq);         // cross-half via permlane32_swap (VALU)
        float w = (t * 16 + c16 < P_N) ? __expf(scq) : 0.f;
        Zp += w;
        #pragma unroll
        for (int s = 0; s < 2; s++)
            #pragma unroll
            for (int u = 0; u < 8; u++)
                acf[s * 8 + u] = fmaf((float)af[s][u], w, acf[s * 8 + u]);  // fma_mix
    }

    // ---- reduce over the 16 pair-columns (c16) within each g-group ----
    #pragma unroll
    for (int msk = 1; msk <= 8; msk <<= 1) {
        Zp += __shfl_xor(Zp, msk);
        #pragma unroll
        for (int u = 0; u < 16; u++) acf[u] += __shfl_xor(acf[u], msk);
    }

    // ---- write afm (fp16) + lr to LDS for the MLP phase ----
    if (c16 == 0) {
        float rZ = 1.f / Zp;
        #pragma unroll
        for (int s = 0; s < 2; s++) {
            half4 o0 = {(_Float16)(acf[s * 8 + 0] * rZ), (_Float16)(acf[s * 8 + 1] * rZ),
                        (_Float16)(acf[s * 8 + 2] * rZ), (_Float16)(acf[s * 8 + 3] * rZ)};
            half4 o1 = {(_Float16)(acf[s * 8 + 4] * rZ), (_Float16)(acf[s * 8 + 5] * rZ),
                        (_Float16)(acf[s * 8 + 6] * rZ), (_Float16)(acf[s * 8 + 7] * rZ)};
            *reinterpret_cast<half4*>(&afmL[wid][s * 32 + g * 8])     = o0;
            *reinterpret_cast<half4*>(&afmL[wid][s * 32 + g * 8 + 4]) = o1;
        }
    }
    #pragma unroll
    for (int off = 32; off; off >>= 1) lv += __shfl_xor(lv, off);
    if (lane == 0) lrL[wid] = lv;
    __syncthreads();

    // ================= MLP phase (in-block, r12-verified head) =============
    // mfma(A,B): D row = g*4+r (= A row index), D col = c16 (= B n index);
    // k-slot (g,u) <-> k = base + 8g + u, identical A and B.
    // Only D rows < 8 are real samples; rows 8-15 dead (afmL zeroed).

    // ---- L0: D[16,256] = afm @ w0 + b0, relu -> h0L. 16 n-tiles / 8 waves.
    {
        half8 af0[2];
        #pragma unroll
        for (int s = 0; s < 2; s++)
            af0[s] = *reinterpret_cast<const half8*>(&afmL[c16][s * 32 + g * 8]);
        #pragma unroll
        for (int q = 0; q < 2; q++) {
            int n = (wid * 2 + q) * 16 + c16;
            half8 bf[2];
            #pragma unroll
            for (int s = 0; s < 2; s++)
                #pragma unroll
                for (int u = 0; u < 8; u++)
                    bf[s][u] = (_Float16)w0[(s * 32 + g * 8 + u) * 256 + n];
            floatx4 acc = {0.f, 0.f, 0.f, 0.f};
            acc = __builtin_amdgcn_mfma_f32_16x16x32_f16(af0[0], bf[0], acc, 0, 0, 0);
            acc = __builtin_amdgcn_mfma_f32_16x16x32_f16(af0[1], bf[1], acc, 0, 0, 0);
            float b0n = b0[n];
            #pragma unroll
            for (int r = 0; r < 4; r++)
                h0L[g * 4 + r][n] = (_Float16)fmaxf(acc[r] + b0n, 0.f);
        }
    }
    __syncthreads();

    // ---- L1: D[16,128] = h0 @ w1 + b1, relu -> h1L. 8 n-tiles / 8 waves.
    {
        int n = wid * 16 + c16;
        floatx4 acc = {0.f, 0.f, 0.f, 0.f};
        #pragma unroll
        for (int ks = 0; ks < 8; ks++) {
            half8 af1 = *reinterpret_cast<const half8*>(&h0L[c16][ks * 32 + g * 8]);
            half8 bf;
            #pragma unroll
            for (int u = 0; u < 8; u++)
                bf[u] = (_Float16)w1[(ks * 32 + g * 8 + u) * 128 + n];
            acc = __builtin_amdgcn_mfma_f32_16x16x32_f16(af1, bf, acc, 0, 0, 0);
        }
        float b1n = b1[n];
        #pragma unroll
        for (int r = 0; r < 4; r++)
            h1L[g * 4 + r][n] = fmaxf(acc[r] + b1n, 0.f);
    }
    __syncthreads();

    // ---- L2: out = h1 @ w2 + b2 + bias + lr. Wave wid -> sample wid. ----
    {
        float part = fmaf(h1L[wid][lane * 2], w2[lane * 2],
                          h1L[wid][lane * 2 + 1] * w2[lane * 2 + 1]);
        #pragma unroll
        for (int off = 32; off; off >>= 1) part += __shfl_xor(part, off);
        if (lane == 0)
            out[blockIdx.x * SPB + wid] = part + b2[0] + bias[0] + lrL[wid];
    }
}

extern "C" void kernel_launch(void* const* d_in, const int* in_sizes, int n_in,
                              void* d_out, int out_size, void* d_ws, size_t ws_size,
                              hipStream_t stream) {
    const int*   x_idx   = (const int*)d_in[0];
    const float* embed_w = (const float*)d_in[1];
    const float* embed_b = (const float*)d_in[2];
    const float* att_w   = (const float*)d_in[3];
    const float* att_b   = (const float*)d_in[4];
    const float* att_p   = (const float*)d_in[5];
    const float* w0      = (const float*)d_in[6];
    const float* b0      = (const float*)d_in[7];
    const float* w1      = (const float*)d_in[8];
    const float* b1      = (const float*)d_in[9];
    const float* w2      = (const float*)d_in[10];
    const float* b2      = (const float*)d_in[11];
    const float* bias    = (const float*)d_in[12];
    float*       out     = (float*)d_out;

    anfm_fused_kernel<<<B_N / SPB, 512, 0, stream>>>(
        x_idx, embed_w, embed_b, att_w, att_b, att_p,
        w0, b0, w1, b1, w2, b2, bias, out);
}